// Round 8
// baseline (150.834 us; speedup 1.0000x reference)
//
#include <hip/hip_runtime.h>
#include <hip/hip_bf16.h>

// Mex forward: B=64,C=64,H=W=64, BLK=(64,3,3), STR=(64,2,2), PAD=(0,1,1),
// NI=256, EPS=1, mean mode. OH=OW=32, K=576, out (64,256,32,32) fp32.
//
// y[n][i] = log( sum_k exp(P[n][k] + O[i][k]) ) - log(576)
// Shift-invariant -> no max pass. Zero-padded entries -> exp(0)=1.
//
// v8: v5 structure, 512-thread blocks. NT stores reverted (v7 showed they
//     stall the store queue at HBM latency and block the epi0/kloop1 region;
//     WRITE_SIZE was unchanged -> the ~55MB write overhead is harness memset
//     drain, not our pattern). 8 waves/block each owning an N=32 instance
//     slice (acc[4][2]); same tile, same B stream, same LDS (2x40KB), but
//     2 blocks/CU x 8 waves = 16 waves/CU (2x v5) at IDENTICAL traffic
//     (v6 proved adding waves by shrinking M doubles B traffic; slicing N
//     within the block does not). Per-thread tile1 prefetch halves to 20
//     float2 -> fits 128-VGPR budget at 4 waves/SIMD. Distance-2 B prefetch
//     kept (free under full unroll).
// v5: 2-tile pipeline: tile1's loads fly under tile0's K-loop; epi0
//     interleaves with kloop1. 2 barriers per block total.
// v3: left pad via in-register ones-select; Bt laid out for coalesced 1 KB
//     wave loads; K-loop fully unrolled.

typedef __bf16 bf16x8 __attribute__((ext_vector_type(8)));
typedef __bf16 bf16x4 __attribute__((ext_vector_type(4)));
typedef float  f32x4  __attribute__((ext_vector_type(4)));

// ---- BtL[(ks*16 + g)*64 + q*16 + t16][j] = bf16(exp(off[i][c][p]))
// where g = inst>>4, c = c8*8+j, ks = 2*p + (c8>>2), q = c8&3.
__global__ void mex_prep_b(const float* __restrict__ off, __bf16* __restrict__ Bt) {
    const int i = blockIdx.x * 4 + (threadIdx.x >> 6);  // instance
    const int c = threadIdx.x & 63;                     // channel
    const int c8 = c >> 3, j = c & 7;
    const int g  = i >> 4, t16 = i & 15;
    const int q  = c8 & 3;
    const float* oi = off + i * 576;
    #pragma unroll
    for (int p = 0; p < 9; ++p) {
        float v = oi[c * 9 + p];                        // original k = c*9 + p
        const int ks    = p * 2 + (c8 >> 2);
        const int chunk = (ks * 16 + g) * 64 + q * 16 + t16;
        Bt[chunk * 8 + j] = (__bf16)__expf(v);
    }
}

// ---- main fused kernel ----------------------------------------------------
__global__ __launch_bounds__(512, 4) void mex_main(
        const float* __restrict__ x,
        const __bf16* __restrict__ Bt,
        float* __restrict__ out) {
    // two buffers: [buf 0..1][hl 0..4][w 0..63][chunk 0..7] bf16x8 = 81920 B
    __shared__ bf16x8 lds8[2 * 2560];

    const int bid = blockIdx.x;      // 0..511
    // XCD-chunked swizzle (512 % 8 == 0 -> bijective)
    const int wid  = ((bid & 7) << 6) | (bid >> 3);
    const int b    = wid >> 3;
    const int j2   = wid & 7;
    const int oh0a = j2 << 2;        // tile0: oh rows oh0a, oh0a+1
    const int oh0b = oh0a + 2;       // tile1: oh rows oh0b, oh0b+1
    const int tid  = threadIdx.x;    // 0..511
    const int wv   = tid >> 6;       // 0..7
    const int lane = tid & 63;

    bf16x8 one8;
    #pragma unroll
    for (int j = 0; j < 8; ++j) one8[j] = (__bf16)1.0f;

    // ---- top pad for tile0 (h_global = -1), only j2 == 0 -----------------
    if (oh0a == 0) lds8[tid] = one8;                 // 512 entries = hl0 row

    // staging geometry: thread t -> w-pair wp (w0 = 2*wp), ch = t>>5 (0..15)
    // covering channels c = ch*4..ch*4+3 = chunk c8 = ch>>1, half = ch&1.
    // Swizzled slot c8 ^ (wp&7) == c8 ^ ((w>>1)&7) for both w0, w0+1.
    const int wp   = tid & 31;
    const int w0   = wp << 1;
    const int ch   = tid >> 5;
    const int c8   = ch >> 1;
    const int half = ch & 1;
    const int c8p  = c8 ^ (wp & 7);
    const float* xb = x + ((size_t)b << 18) + w0;   // + c*4096 + h*64

    // ---- stage tile0: x -> exp -> bf16 -> swizzled LDS (chained) ---------
    #pragma unroll
    for (int hl = 0; hl < 5; ++hl) {
        const int hg = 2 * oh0a - 1 + hl;           // -1..31
        if (hg >= 0) {                              // block-uniform
            const float* xp = xb + (hg << 6);
            float2 v[4];
            #pragma unroll
            for (int k = 0; k < 4; ++k)
                v[k] = *(const float2*)(xp + (((ch << 2) + k) << 12));
            bf16x4 ca, cb;
            #pragma unroll
            for (int k = 0; k < 4; ++k) {
                ca[k] = (__bf16)__expf(v[k].x);
                cb[k] = (__bf16)__expf(v[k].y);
            }
            __bf16* bb = (__bf16*)(lds8 + hl * 512 + w0 * 8 + c8p) + (half << 2);
            *(bf16x4*)bb        = ca;     // w = w0
            *(bf16x4*)(bb + 64) = cb;     // w = w0+1 (next chunk slot, +8*8)
        }
    }

    // ---- issue ALL tile1 loads now; they fly under tile0's K-loop --------
    float2 v1[20];
    #pragma unroll
    for (int hl = 0; hl < 5; ++hl) {
        const float* xp = xb + ((2 * oh0b - 1 + hl) << 6);  // rows 3..63
        #pragma unroll
        for (int k = 0; k < 4; ++k)
            v1[hl * 4 + k] = *(const float2*)(xp + (((ch << 2) + k) << 12));
    }

    // ---- first B fragments (distance-2 pipeline) -------------------------
    const bf16x8* __restrict__ Btv = (const bf16x8*)Bt;
    const int g0 = wv << 1;          // instance-group base (inst>>4)
    bf16x8 b0[2], b1[2];
    #pragma unroll
    for (int nt = 0; nt < 2; ++nt) {
        b0[nt] = Btv[(g0 + nt) * 64 + lane];             // ks = 0
        b1[nt] = Btv[(16 + g0 + nt) * 64 + lane];        // ks = 1
    }

    const int t16 = tid & 15;
    const int q   = (tid >> 4) & 3;
    int hb[4], wo2[4];
    #pragma unroll
    for (int mt = 0; mt < 4; ++mt) {
        const int m = mt * 16 + t16;
        wo2[mt] = (m & 31) << 1;      // 2*ow
        hb[mt]  = (m >> 5) << 7;      // (2*ohl) * 64
    }
    const float lK = 6.356107660695891f;   // log(576)

    // K-loop over one staged buffer; B rotates through b0/b1/b2 (dist 2)
    auto kloop = [&](const bf16x8* __restrict__ L, f32x4 (&acc)[4][2],
                     bf16x8 (&bc)[2], bf16x8 (&bn)[2]) {
        #pragma unroll
        for (int ks = 0; ks < 18; ++ks) {
            const int p  = ks >> 1;
            const int fh = (p * 11) >> 5;          // p/3 (const after unroll)
            const int fw = p - fh * 3;
            const int ccq = ((ks & 1) << 2) + q;
            bf16x8 a[4];
            #pragma unroll
            for (int mt = 0; mt < 4; ++mt) {
                const int wc  = wo2[mt] + fw - 1;  // w_global, -1..63
                const int pad = wc < 0;            // only fw==0 & ow==0
                const int wcl = pad ? 0 : wc;
                const int row = hb[mt] + fh * 64 + wcl;  // (2*ohl+fh)*64 + w
                bf16x8 vv = L[row * 8 + (ccq ^ ((wcl >> 1) & 7))];
                a[mt] = pad ? one8 : vv;
            }
            bf16x8 b2[2];
            if (ks < 16) {
                #pragma unroll
                for (int nt = 0; nt < 2; ++nt)
                    b2[nt] = Btv[((ks + 2) * 16 + g0 + nt) * 64 + lane];
            }
            #pragma unroll
            for (int mt = 0; mt < 4; ++mt)
                #pragma unroll
                for (int nt = 0; nt < 2; ++nt)
                    acc[mt][nt] = __builtin_amdgcn_mfma_f32_16x16x32_bf16(
                        a[mt], bc[nt], acc[mt][nt], 0, 0, 0);
            #pragma unroll
            for (int nt = 0; nt < 2; ++nt) { bc[nt] = bn[nt]; bn[nt] = b2[nt]; }
        }
    };

    // direct-store epilogue: y = log(S) - log(576)
    auto epilogue = [&](f32x4 (&acc)[4][2], int oh0) {
        #pragma unroll
        for (int mt = 0; mt < 4; ++mt) {
            const int m   = mt * 16 + (q << 2);    // C/D: row = q*4 + reg
            const int ohl = m >> 5;
            const int owi = m & 31;
            const int orow = (oh0 + ohl) * 32 + owi;
            #pragma unroll
            for (int nt = 0; nt < 2; ++nt) {
                const int inst = wv * 32 + nt * 16 + t16;  // C/D: col = t16
                f32x4 r;
                #pragma unroll
                for (int j = 0; j < 4; ++j)
                    r[j] = __logf(acc[mt][nt][j]) - lK;
                *(f32x4*)(out + (((size_t)b * 256 + inst) * 1024 + orow)) = r;
            }
        }
    };

    __syncthreads();   // B0: buf0 staged

    f32x4 acc0[4][2];
    #pragma unroll
    for (int mt = 0; mt < 4; ++mt)
        #pragma unroll
        for (int nt = 0; nt < 2; ++nt) acc0[mt][nt] = (f32x4)(0.0f);
    kloop(lds8, acc0, b0, b1);

    // ---- finish-stage tile1 (loads have landed under the K-loop) ---------
    #pragma unroll
    for (int hl = 0; hl < 5; ++hl) {
        bf16x4 ca, cb;
        #pragma unroll
        for (int k = 0; k < 4; ++k) {
            ca[k] = (__bf16)__expf(v1[hl * 4 + k].x);
            cb[k] = (__bf16)__expf(v1[hl * 4 + k].y);
        }
        __bf16* bb = (__bf16*)(lds8 + 2560 + hl * 512 + w0 * 8 + c8p) + (half << 2);
        *(bf16x4*)bb        = ca;
        *(bf16x4*)(bb + 64) = cb;
    }
    #pragma unroll
    for (int nt = 0; nt < 2; ++nt) {
        b0[nt] = Btv[(g0 + nt) * 64 + lane];             // ks = 0
        b1[nt] = Btv[(16 + g0 + nt) * 64 + lane];        // ks = 1
    }

    __syncthreads();   // B1: buf1 staged

    // epilogue(t0) sits in the same scheduling region as kloop(t1):
    // logf/global-stores interleave with MFMA/ds_reads.
    epilogue(acc0, oh0a);

    f32x4 acc1[4][2];
    #pragma unroll
    for (int mt = 0; mt < 4; ++mt)
        #pragma unroll
        for (int nt = 0; nt < 2; ++nt) acc1[mt][nt] = (f32x4)(0.0f);
    kloop(lds8 + 2560, acc1, b0, b1);

    epilogue(acc1, oh0b);
}

extern "C" void kernel_launch(void* const* d_in, const int* in_sizes, int n_in,
                              void* d_out, int out_size, void* d_ws, size_t ws_size,
                              hipStream_t stream) {
    const float* x   = (const float*)d_in[0];   // (64,64,64,64) fp32
    const float* off = (const float*)d_in[1];   // (1,256,64,3,3) fp32
    float* out = (float*)d_out;                 // (64,256,32,32) fp32
    __bf16* Bt = (__bf16*)d_ws;                 // 294912 B

    mex_prep_b<<<64, 256, 0, stream>>>(off, Bt);
    mex_main<<<512, 512, 0, stream>>>(x, Bt, out);
}